// Round 11
// baseline (221.721 us; speedup 1.0000x reference)
//
#include <hip/hip_runtime.h>
#include <hip/hip_bf16.h>

#define NROWS 2048
#define CCH   64
#define FDIM  256
#define CF    16384   // C*F
#define EPSV  1e-3f

typedef __attribute__((ext_vector_type(8))) short  short8;
typedef __attribute__((ext_vector_type(4))) float  f32x4;

__device__ __forceinline__ ushort f2bf(float f) {
  union { float f; unsigned u; } v; v.f = f;
  unsigned r = v.u + 0x7fffu + ((v.u >> 16) & 1u);
  return (ushort)(r >> 16);
}
__device__ __forceinline__ float bf_lo(unsigned u) {
  union { unsigned u; float f; } v; v.u = u << 16; return v.f;
}
__device__ __forceinline__ float bf_hi(unsigned u) {
  union { unsigned u; float f; } v; v.u = u & 0xffff0000u; return v.f;
}
__device__ __forceinline__ unsigned pk2(float a, float b) {
  __hip_bfloat162 h = __float22bfloat162_rn(float2{a, b});
  union { __hip_bfloat162 h; unsigned u; } cv; cv.h = h; return cv.u;
}
__device__ __forceinline__ void gll16(const void* g, void* l) {
  __builtin_amdgcn_global_load_lds(
      (const __attribute__((address_space(1))) unsigned*)g,
      (__attribute__((address_space(3))) unsigned*)l, 16, 0, 0);
}

// ---------------- BN0 stats partials (no atomics) ----------------
__global__ __launch_bounds__(256) void bn_stats_part(const float* __restrict__ src,
                                                     float* __restrict__ ps,
                                                     float* __restrict__ pq) {
  int cb = blockIdx.x * 256 + threadIdx.x;       // float4 col index 0..4095
  int by = blockIdx.y;
  const float4* p = (const float4*)src + (size_t)(by * 16) * (CF / 4) + cb;
  float s0 = 0, s1 = 0, s2 = 0, s3 = 0, q0 = 0, q1 = 0, q2 = 0, q3 = 0;
#pragma unroll
  for (int i = 0; i < 16; ++i) {
    float4 v = p[(size_t)i * (CF / 4)];
    s0 += v.x; q0 += v.x * v.x;
    s1 += v.y; q1 += v.y * v.y;
    s2 += v.z; q2 += v.z * v.z;
    s3 += v.w; q3 += v.w * v.w;
  }
  float4 sv; sv.x = s0; sv.y = s1; sv.z = s2; sv.w = s3;
  float4 qv; qv.x = q0; qv.y = q1; qv.z = q2; qv.w = q3;
  ((float4*)(ps + (size_t)by * CF))[cb] = sv;
  ((float4*)(pq + (size_t)by * CF))[cb] = qv;
}

// reduce nparts partials -> scale/shift. grid 64 x 256.
__global__ __launch_bounds__(256) void bn_finalize(const float* __restrict__ ps,
                                                   const float* __restrict__ pq,
                                                   int nparts,
                                                   const float* __restrict__ g,
                                                   const float* __restrict__ be,
                                                   float* __restrict__ scale,
                                                   float* __restrict__ shift) {
  int i = blockIdx.x * 256 + threadIdx.x;
  float s = 0, q = 0;
  for (int j = 0; j < nparts; ++j) {
    s += ps[(size_t)j * CF + i];
    q += pq[(size_t)j * CF + i];
  }
  float mean = s * (1.0f / NROWS);
  float var  = q * (1.0f / NROWS) - mean * mean;
  float sc   = g[i] * rsqrtf(var + EPSV);
  scale[i] = sc;
  shift[i] = be[i] - mean * sc;
}

// ---------------- both weights f32 -> bf16, one launch ----------------
__global__ __launch_bounds__(256) void cvt2_f32_bf16(const float* __restrict__ w0,
                                                     const float* __restrict__ w1,
                                                     ushort* __restrict__ o0,
                                                     ushort* __restrict__ o1, int n4) {
  size_t stride = (size_t)gridDim.x * blockDim.x;
  for (size_t i = (size_t)blockIdx.x * 256 + threadIdx.x; i < (size_t)(2 * n4); i += stride) {
    const float* src = (i < (size_t)n4) ? w0 : w1;
    ushort* dst = (i < (size_t)n4) ? o0 : o1;
    size_t j = (i < (size_t)n4) ? i : i - n4;
    float4 v = ((const float4*)src)[j];
    ushort4 u;
    u.x = f2bf(v.x); u.y = f2bf(v.y); u.z = f2bf(v.z); u.w = f2bf(v.w);
    ((ushort4*)dst)[j] = u;
  }
}

// ---------------- fused batched channel GEMM (4 blocks/CU) ----------------
// Tile: BM=128 x BN=64 x K=256. Grid 4096 = 16bm x 4bn x 64c. 4 waves, each
// 32 rows x 64 cols (m=2, n=4 frags). W [64][256] bf16 = 32KB staged ONCE
// (global_load_lds, XOR-swizzled src+reads) -> zero K-loop barriers.
// LDS ~37KB => 4 blocks/CU (16 waves/CU). launch_bounds(256,2) -> VGPR<=128.
// A: quarter-granular (2 ks) double-buffered register pipeline, issue pinned
// by sched_barrier(0). MODE 0: A=relu(bn0(x)) f32; out ybf + BN1 partials.
// MODE 1: A=relu(bn1(ybf)) bf16; out = xres + acc + bias.
template <int MODE>
__global__ __launch_bounds__(256, 2) void gemm_fused(const void* __restrict__ Asrc,
                                                     const ushort* __restrict__ W,
                                                     const float* __restrict__ bias,
                                                     const float* __restrict__ scale,
                                                     const float* __restrict__ shift,
                                                     const float* __restrict__ xres,
                                                     ushort* __restrict__ Ybf,
                                                     float* __restrict__ outf,
                                                     float* __restrict__ ps1,
                                                     float* __restrict__ pq1) {
  __shared__ __align__(16) ushort Ws[2][64 * 128];    // 32KB; aliased as Cs f32[128][64]
  __shared__ float scl[256], shf[256];                // 2KB
  __shared__ float sstat[2][4][4][16];                // 2KB (MODE0)

  const int t = threadIdx.x;
  const int lane = t & 63, wid = t >> 6;
  const int lm = lane & 15, lg = lane >> 4;

  // bijective XCD swizzle (nwg=4096): wg = c*64 + bn*16 + bm; 8 c's per XCD
  const int h  = blockIdx.x;
  const int wg = ((h & 7) << 9) | (h >> 3);
  const int bm = wg & 15, bn = (wg >> 4) & 3, c = wg >> 6;

  scl[t] = scale[c * FDIM + t];
  shf[t] = shift[c * FDIM + t];

  // ---- W staging: BOTH halves at once, 8 gll16/thread, one barrier ----
  const int srow = t >> 4;            // 0..15
  const int sb   = (t & 15) * 16;     // 0..240 byte-in-half-row
  const int gsb  = sb ^ ((srow & 7) << 4);
  const char* Wrow = (const char*)(W + ((size_t)c * FDIM + bn * 64) * FDIM);
  char* Ws0 = (char*)&Ws[0][0];
  char* Ws1 = (char*)&Ws[1][0];
#pragma unroll
  for (int i = 0; i < 4; ++i) {
    const int row = i * 16 + srow;   // 0..63
    gll16(Wrow + (size_t)row * 512 + gsb,       Ws0 + row * 256 + sb);
    gll16(Wrow + (size_t)row * 512 + 256 + gsb, Ws1 + row * 256 + sb);
  }

  float bregs[4];
#pragma unroll
  for (int n = 0; n < 4; ++n)
    bregs[n] = bias[c * FDIM + bn * 64 + n * 16 + lm];

  const float*  AbF[2];
  const ushort* AbU[2];
#pragma unroll
  for (int m = 0; m < 2; ++m) {
    const size_t rowoff = (size_t)(bm * 128 + wid * 32 + m * 16 + lm) * CF + c * FDIM + lg * 8;
    AbF[m] = (const float*)Asrc + rowoff;
    AbU[m] = (const ushort*)Asrc + rowoff;
  }

  // ---- A quarter buffers (2 ks each), two alternating named sets ----
  float4 qa_f[2][2][2], qb_f[2][2][2];   // MODE0 raw f32
  uint4  qa_u[2][2],    qb_u[2][2];      // MODE1 raw bf16x8

#define LOADQ(buf, kq)                                                      \
  _Pragma("unroll")                                                         \
  for (int k2 = 0; k2 < 2; ++k2)                                            \
    _Pragma("unroll")                                                       \
    for (int m = 0; m < 2; ++m) {                                           \
      if (MODE == 0) {                                                      \
        buf##_f[k2][m][0] = *(const float4*)(AbF[m] + ((kq) * 2 + k2) * 32);     \
        buf##_f[k2][m][1] = *(const float4*)(AbF[m] + ((kq) * 2 + k2) * 32 + 4); \
      } else {                                                              \
        buf##_u[k2][m] = *(const uint4*)(AbU[m] + ((kq) * 2 + k2) * 32);    \
      }                                                                     \
    }                                                                       \
  __builtin_amdgcn_sched_barrier(0);

  // conv one ks from buf then do its 8 MFMAs (W half/offset compile-time)
#define CMF(buf, kq, k2)                                                    \
  {                                                                         \
    const int ksg = (kq) * 2 + (k2);                                        \
    float4 sc0 = *(const float4*)&scl[ksg * 32 + lg * 8];                   \
    float4 sc1 = *(const float4*)&scl[ksg * 32 + lg * 8 + 4];               \
    float4 sh0 = *(const float4*)&shf[ksg * 32 + lg * 8];                   \
    float4 sh1 = *(const float4*)&shf[ksg * 32 + lg * 8 + 4];               \
    short8 af[2];                                                           \
    _Pragma("unroll")                                                       \
    for (int m = 0; m < 2; ++m) {                                           \
      float v0, v1, v2, v3, v4, v5, v6, v7;                                 \
      if (MODE == 0) {                                                      \
        float4 a0 = buf##_f[k2][m][0];                                      \
        float4 a1 = buf##_f[k2][m][1];                                      \
        v0 = a0.x; v1 = a0.y; v2 = a0.z; v3 = a0.w;                         \
        v4 = a1.x; v5 = a1.y; v6 = a1.z; v7 = a1.w;                         \
      } else {                                                              \
        uint4 u = buf##_u[k2][m];                                           \
        v0 = bf_lo(u.x); v1 = bf_hi(u.x); v2 = bf_lo(u.y); v3 = bf_hi(u.y); \
        v4 = bf_lo(u.z); v5 = bf_hi(u.z); v6 = bf_lo(u.w); v7 = bf_hi(u.w); \
      }                                                                     \
      v0 = fmaxf(fmaf(v0, sc0.x, sh0.x), 0.f);                              \
      v1 = fmaxf(fmaf(v1, sc0.y, sh0.y), 0.f);                              \
      v2 = fmaxf(fmaf(v2, sc0.z, sh0.z), 0.f);                              \
      v3 = fmaxf(fmaf(v3, sc0.w, sh0.w), 0.f);                              \
      v4 = fmaxf(fmaf(v4, sc1.x, sh1.x), 0.f);                              \
      v5 = fmaxf(fmaf(v5, sc1.y, sh1.y), 0.f);                              \
      v6 = fmaxf(fmaf(v6, sc1.z, sh1.z), 0.f);                              \
      v7 = fmaxf(fmaf(v7, sc1.w, sh1.w), 0.f);                              \
      union { short8 s; unsigned u[4]; } pkd;                               \
      pkd.u[0] = pk2(v0, v1); pkd.u[1] = pk2(v2, v3);                       \
      pkd.u[2] = pk2(v4, v5); pkd.u[3] = pk2(v6, v7);                       \
      af[m] = pkd.s;                                                        \
    }                                                                       \
    const char* WsH = (ksg < 4) ? Ws0 : Ws1;                                \
    const int ksl = ksg & 3;                                                \
    short8 bv[4];                                                           \
    _Pragma("unroll")                                                       \
    for (int n = 0; n < 4; ++n) {                                           \
      const int ro = n * 16 + lm;                                           \
      const int byt = (ksl * 64 + lg * 16) ^ ((ro & 7) << 4);               \
      bv[n] = *(const short8*)(WsH + ro * 256 + byt);                       \
    }                                                                       \
    _Pragma("unroll")                                                       \
    for (int m = 0; m < 2; ++m)                                             \
      _Pragma("unroll")                                                     \
      for (int n = 0; n < 4; ++n)                                           \
        acc[m][n] = __builtin_amdgcn_mfma_f32_16x16x32_bf16(af[m], bv[n],   \
                                                            acc[m][n], 0, 0, 0); \
  }

  LOADQ(qa, 0)   // hides under W-stage drain

  f32x4 acc[2][4];
#pragma unroll
  for (int m = 0; m < 2; ++m)
#pragma unroll
    for (int n = 0; n < 4; ++n) acc[m][n] = (f32x4){0.f, 0.f, 0.f, 0.f};

  __syncthreads();   // W fully staged + scl/shf ready; NO more K-loop barriers

  LOADQ(qb, 1)
  CMF(qa, 0, 0) CMF(qa, 0, 1)
  LOADQ(qa, 2)
  CMF(qb, 1, 0) CMF(qb, 1, 1)
  LOADQ(qb, 3)
  CMF(qa, 2, 0) CMF(qa, 2, 1)
  CMF(qb, 3, 0) CMF(qb, 3, 1)

  if (MODE == 0) {
    // ---- BN1 column partial stats from f32 acc ----
#pragma unroll
    for (int n = 0; n < 4; ++n) {
      float ss = 0, qq = 0;
#pragma unroll
      for (int m = 0; m < 2; ++m)
#pragma unroll
        for (int j = 0; j < 4; ++j) {
          float v = acc[m][n][j] + bregs[n];
          ss += v; qq += v * v;
        }
      ss += __shfl_xor(ss, 16); ss += __shfl_xor(ss, 32);
      qq += __shfl_xor(qq, 16); qq += __shfl_xor(qq, 32);
      if (lg == 0) {
        sstat[0][wid][n][lm] = ss;
        sstat[1][wid][n][lm] = qq;
      }
    }
  }
  __syncthreads();   // all Ws reads done + sstat written; Ws reusable as Cs

  // ---- C -> LDS f32 [128][64], swz col^(((row>>2)&3)<<4) -> 2-way max ----
  float* Cs = (float*)&Ws[0][0];   // 32KB
#pragma unroll
  for (int m = 0; m < 2; ++m) {
    const int rbase = wid * 32 + m * 16 + lg * 4;
    const int xd = lg << 4;        // == ((rbase>>2)&3)<<4
#pragma unroll
    for (int n = 0; n < 4; ++n) {
      const int col = n * 16 + lm;
#pragma unroll
      for (int j = 0; j < 4; ++j)
        Cs[(rbase + j) * 64 + (col ^ xd)] = acc[m][n][j] + bregs[n];
    }
  }
  __syncthreads();

  // ---- coalesced writeout: 8 thr/row, 32 rows/pass, 4 passes ----
  const int rt = t >> 3;           // 0..31
  const int pcol = (t & 7) * 8;    // 0..56
#pragma unroll
  for (int rb = 0; rb < 4; ++rb) {
    const int row = rb * 32 + rt;
    const int xd = ((row >> 2) & 3) << 4;
    f32x4 v0 = *(const f32x4*)&Cs[row * 64 + (pcol ^ xd)];
    f32x4 v1 = *(const f32x4*)&Cs[row * 64 + ((pcol + 4) ^ xd)];
    const size_t gofs = (size_t)(bm * 128 + row) * CF + c * FDIM + bn * 64 + pcol;
    if (MODE == 0) {
      uint4 u;
      u.x = pk2(v0[0], v0[1]); u.y = pk2(v0[2], v0[3]);
      u.z = pk2(v1[0], v1[1]); u.w = pk2(v1[2], v1[3]);
      *(uint4*)(Ybf + gofs) = u;
    } else {
      float4 x0 = *(const float4*)(xres + gofs);
      float4 x1 = *(const float4*)(xres + gofs + 4);
      float4 o0, o1;
      o0.x = x0.x + v0[0]; o0.y = x0.y + v0[1]; o0.z = x0.z + v0[2]; o0.w = x0.w + v0[3];
      o1.x = x1.x + v1[0]; o1.y = x1.y + v1[1]; o1.z = x1.z + v1[2]; o1.w = x1.w + v1[3];
      *(float4*)(outf + gofs) = o0;
      *(float4*)(outf + gofs + 4) = o1;
    }
  }

  if (MODE == 0) {
    // ---- partial stats writeout: 128 thr = 2 stats x 4n x 16 cols ----
    if (t < 128) {
      const int stat = t >> 6;
      const int idx = t & 63;
      const int n = idx >> 4, lmm = idx & 15;
      float v = sstat[stat][0][n][lmm] + sstat[stat][1][n][lmm] +
                sstat[stat][2][n][lmm] + sstat[stat][3][n][lmm];
      float* dst = stat ? pq1 : ps1;
      dst[(size_t)bm * CF + c * FDIM + bn * 64 + n * 16 + lmm] = v;
    }
  }
}

// ---------------- launch ----------------
extern "C" void kernel_launch(void* const* d_in, const int* in_sizes, int n_in,
                              void* d_out, int out_size, void* d_ws, size_t ws_size,
                              hipStream_t stream) {
  const float* x   = (const float*)d_in[0];
  const float* w0  = (const float*)d_in[1];
  const float* b0  = (const float*)d_in[2];
  const float* w1  = (const float*)d_in[3];
  const float* b1  = (const float*)d_in[4];
  const float* g0  = (const float*)d_in[5];
  const float* be0 = (const float*)d_in[6];
  const float* g1  = (const float*)d_in[7];
  const float* be1 = (const float*)d_in[8];
  float* out = (float*)d_out;

  char* ws = (char*)d_ws;
  float* ps0    = (float*)ws;                         // 128*CF
  float* pq0    = ps0 + (size_t)128 * CF;             // 128*CF
  float* ps1    = pq0 + (size_t)128 * CF;             // 16*CF
  float* pq1    = ps1 + (size_t)16 * CF;              // 16*CF
  float* scale0 = pq1 + (size_t)16 * CF;
  float* shift0 = scale0 + CF;
  float* scale1 = shift0 + CF;
  float* shift1 = scale1 + CF;
  ushort* w0bf = (ushort*)(shift1 + CF);
  ushort* w1bf = w0bf + (size_t)CCH * FDIM * FDIM;
  ushort* ybf  = w1bf + (size_t)CCH * FDIM * FDIM;

  const int NW4 = CCH * FDIM * FDIM / 4;
  cvt2_f32_bf16<<<4096, 256, 0, stream>>>(w0, w1, w0bf, w1bf, NW4);

  // BN0 stats over x (no atomics)
  bn_stats_part<<<dim3(16, 128), 256, 0, stream>>>(x, ps0, pq0);
  bn_finalize<<<64, 256, 0, stream>>>(ps0, pq0, 128, g0, be0, scale0, shift0);

  // linear0 fused: A=relu(bn0(x)), out ybf + BN1 partials
  gemm_fused<0><<<4096, 256, 0, stream>>>(
      x, w0bf, b0, scale0, shift0, nullptr, ybf, nullptr, ps1, pq1);

  bn_finalize<<<64, 256, 0, stream>>>(ps1, pq1, 16, g1, be1, scale1, shift1);

  // linear1 fused: A=relu(bn1(ybf)), out = x + acc + b1
  gemm_fused<1><<<4096, 256, 0, stream>>>(
      ybf, w1bf, b1, scale1, shift1, x, nullptr, out, nullptr, nullptr);
}

// Round 12
// 206.975 us; speedup vs baseline: 1.0712x; 1.0712x over previous
//
#include <hip/hip_runtime.h>
#include <hip/hip_bf16.h>

#define NROWS 2048
#define CCH   64
#define FDIM  256
#define CF    16384   // C*F
#define EPSV  1e-3f

typedef __attribute__((ext_vector_type(8))) short  short8;
typedef __attribute__((ext_vector_type(4))) float  f32x4;

__device__ __forceinline__ ushort f2bf(float f) {
  union { float f; unsigned u; } v; v.f = f;
  unsigned r = v.u + 0x7fffu + ((v.u >> 16) & 1u);
  return (ushort)(r >> 16);
}
__device__ __forceinline__ float bf_lo(unsigned u) {
  union { unsigned u; float f; } v; v.u = u << 16; return v.f;
}
__device__ __forceinline__ float bf_hi(unsigned u) {
  union { unsigned u; float f; } v; v.u = u & 0xffff0000u; return v.f;
}
__device__ __forceinline__ unsigned pk2(float a, float b) {
  __hip_bfloat162 h = __float22bfloat162_rn(float2{a, b});
  union { __hip_bfloat162 h; unsigned u; } cv; cv.h = h; return cv.u;
}
__device__ __forceinline__ void gll16(const void* g, void* l) {
  __builtin_amdgcn_global_load_lds(
      (const __attribute__((address_space(1))) unsigned*)g,
      (__attribute__((address_space(3))) unsigned*)l, 16, 0, 0);
}

// ---------------- BN0 stats + x -> xt bf16 (c,n,f) transpose-pack ----------------
// grid (64 c, 16 nblk), 256 thr. Thread: col-group cg (4 f-cols), 32 rows.
// Reads: per row, wave spans 1KB contiguous. Writes: per row, wave spans 512B
// contiguous in xt (c-major) -> fully sequential slabs per block.
__global__ __launch_bounds__(256) void stats_xt(const float* __restrict__ x,
                                                ushort* __restrict__ xt,
                                                float* __restrict__ ps,
                                                float* __restrict__ pq) {
  __shared__ float red[2][4][64][4];   // 8KB
  const int c  = blockIdx.x;
  const int nb = blockIdx.y;
  const int t  = threadIdx.x;
  const int cg = t & 63;               // float4 col group: f = cg*4..cg*4+3
  const int rg = t >> 6;               // 0..3

  const float4* src = (const float4*)x;         // idx = row*4096 + c*64 + cg
  ushort4* dst = (ushort4*)xt;                  // idx = c*131072 + row*64 + cg
  float s0 = 0, s1 = 0, s2 = 0, s3 = 0, q0 = 0, q1 = 0, q2 = 0, q3 = 0;
#pragma unroll 8
  for (int i = 0; i < 32; ++i) {
    const int row = nb * 128 + rg * 32 + i;
    float4 v = src[(size_t)row * 4096 + c * 64 + cg];
    s0 += v.x; q0 += v.x * v.x;
    s1 += v.y; q1 += v.y * v.y;
    s2 += v.z; q2 += v.z * v.z;
    s3 += v.w; q3 += v.w * v.w;
    ushort4 u;
    u.x = f2bf(v.x); u.y = f2bf(v.y); u.z = f2bf(v.z); u.w = f2bf(v.w);
    dst[(size_t)c * 131072 + row * 64 + cg] = u;
  }
  red[0][rg][cg][0] = s0; red[0][rg][cg][1] = s1;
  red[0][rg][cg][2] = s2; red[0][rg][cg][3] = s3;
  red[1][rg][cg][0] = q0; red[1][rg][cg][1] = q1;
  red[1][rg][cg][2] = q2; red[1][rg][cg][3] = q3;
  __syncthreads();
  if (t < 128) {
    const int which = t >> 6;          // 0=s, 1=q
    const int g = t & 63;
    float* dstp = which ? pq : ps;
#pragma unroll
    for (int j = 0; j < 4; ++j) {
      float v = red[which][0][g][j] + red[which][1][g][j] +
                red[which][2][g][j] + red[which][3][g][j];
      dstp[(size_t)nb * CF + c * FDIM + g * 4 + j] = v;
    }
  }
}

// reduce nparts partials -> scale/shift. grid 64 x 256.
__global__ __launch_bounds__(256) void bn_finalize(const float* __restrict__ ps,
                                                   const float* __restrict__ pq,
                                                   int nparts,
                                                   const float* __restrict__ g,
                                                   const float* __restrict__ be,
                                                   float* __restrict__ scale,
                                                   float* __restrict__ shift) {
  int i = blockIdx.x * 256 + threadIdx.x;
  float s = 0, q = 0;
  for (int j = 0; j < nparts; ++j) {
    s += ps[(size_t)j * CF + i];
    q += pq[(size_t)j * CF + i];
  }
  float mean = s * (1.0f / NROWS);
  float var  = q * (1.0f / NROWS) - mean * mean;
  float sc   = g[i] * rsqrtf(var + EPSV);
  scale[i] = sc;
  shift[i] = be[i] - mean * sc;
}

// ---------------- both weights f32 -> bf16, one launch ----------------
__global__ __launch_bounds__(256) void cvt2_f32_bf16(const float* __restrict__ w0,
                                                     const float* __restrict__ w1,
                                                     ushort* __restrict__ o0,
                                                     ushort* __restrict__ o1, int n4) {
  size_t stride = (size_t)gridDim.x * blockDim.x;
  for (size_t i = (size_t)blockIdx.x * 256 + threadIdx.x; i < (size_t)(2 * n4); i += stride) {
    const float* src = (i < (size_t)n4) ? w0 : w1;
    ushort* dst = (i < (size_t)n4) ? o0 : o1;
    size_t j = (i < (size_t)n4) ? i : i - n4;
    float4 v = ((const float4*)src)[j];
    ushort4 u;
    u.x = f2bf(v.x); u.y = f2bf(v.y); u.z = f2bf(v.z); u.w = f2bf(v.w);
    ((ushort4*)dst)[j] = u;
  }
}

// ---------------- fused batched channel GEMM, (c,n,f) operand layout ----------------
// Tile: BM=128 x BN=128 x K=256. Grid 2048 = 16bm x 2bn x 64c. 4 waves, each
// 32 rows x 128 cols (m=2, n=8 frags). W [128][256] bf16 staged as two 32KB
// k-halves via global_load_lds (linear dest, XOR-swizzled src+reads).
// A: bf16 from channel-major (c,n,f) buffer -> wave loads span ~8KB contiguous.
// Half-batch register pipeline (LOADH/CONVH pinned by sched_barrier).
// BN(scale,shift)+ReLU applied on unpacked A before pack to MFMA frags.
// MODE 0: out ybf (c,n,f) bf16 + BN1 partials. MODE 1: out(n,cf) = xres + acc + b.
template <int MODE>
__global__ __launch_bounds__(256, 2) void gemm_fused(const ushort* __restrict__ Act,
                                                     const ushort* __restrict__ W,
                                                     const float* __restrict__ bias,
                                                     const float* __restrict__ scale,
                                                     const float* __restrict__ shift,
                                                     const float* __restrict__ xres,
                                                     ushort* __restrict__ Ybf,
                                                     float* __restrict__ outf,
                                                     float* __restrict__ ps1,
                                                     float* __restrict__ pq1) {
  __shared__ __align__(16) ushort Ws[2][128 * 128];   // 64KB; reused as Cs f32[128][128]
  __shared__ float scl[256], shf[256];                // 2KB
  __shared__ float sstat[2][4][8][16];                // 4KB (MODE0)

  const int t = threadIdx.x;
  const int lane = t & 63, wid = t >> 6;
  const int lm = lane & 15, lg = lane >> 4;

  // bijective XCD swizzle (nwg=2048): XCD j gets wg in [j*256,(j+1)*256)
  const int h  = blockIdx.x;
  const int wg = ((h & 7) << 8) | (h >> 3);
  const int bm = wg & 15, bn = (wg >> 4) & 1, c = wg >> 5;

  scl[t] = scale[c * FDIM + t];
  shf[t] = shift[c * FDIM + t];

  // W staging: per half 32KB = 256thr x 8 chunks x 16B, linear LDS dest.
  const int srow = t >> 4;            // 0..15
  const int sb   = (t & 15) * 16;     // 0..240 byte-in-half-row
  const int gsb  = sb ^ ((srow & 7) << 4);
  const char* Wrow = (const char*)(W + ((size_t)c * FDIM + bn * 128) * FDIM);
  char* Ws0 = (char*)&Ws[0][0];
  char* Ws1 = (char*)&Ws[1][0];

#pragma unroll
  for (int i = 0; i < 8; ++i) {
    const int row = i * 16 + srow;
    gll16(Wrow + (size_t)row * 512 + gsb, Ws0 + row * 256 + sb);
  }

  float bregs[8];
#pragma unroll
  for (int n = 0; n < 8; ++n)
    bregs[n] = bias[c * FDIM + bn * 128 + n * 16 + lm];

  // A base: channel-major (c,n,f) bf16
  const ushort* AbU[2];
#pragma unroll
  for (int m = 0; m < 2; ++m)
    AbU[m] = Act + (size_t)c * (NROWS * FDIM)
                 + (size_t)(bm * 128 + wid * 32 + m * 16 + lm) * FDIM + lg * 8;

  // ---- A half-batch buffers (explicit, static-indexed) ----
  uint4  lu[4][2];      // raw bf16x8 per (ks,m), 32 VGPR
  short8 af[4][2];      // converted fragments, 32 VGPR

#define LOADH(kb)                                                           \
  _Pragma("unroll")                                                         \
  for (int ks = 0; ks < 4; ++ks)                                            \
    _Pragma("unroll")                                                       \
    for (int m = 0; m < 2; ++m)                                             \
      lu[ks][m] = *(const uint4*)(AbU[m] + ((kb) + ks) * 32);               \
  __builtin_amdgcn_sched_barrier(0);

#define CONVH(kb)                                                           \
  _Pragma("unroll")                                                         \
  for (int ks = 0; ks < 4; ++ks) {                                          \
    float4 sc0 = *(const float4*)&scl[((kb) + ks) * 32 + lg * 8];           \
    float4 sc1 = *(const float4*)&scl[((kb) + ks) * 32 + lg * 8 + 4];       \
    float4 sh0 = *(const float4*)&shf[((kb) + ks) * 32 + lg * 8];           \
    float4 sh1 = *(const float4*)&shf[((kb) + ks) * 32 + lg * 8 + 4];       \
    _Pragma("unroll")                                                       \
    for (int m = 0; m < 2; ++m) {                                           \
      uint4 u = lu[ks][m];                                                  \
      float v0 = bf_lo(u.x), v1 = bf_hi(u.x), v2 = bf_lo(u.y), v3 = bf_hi(u.y); \
      float v4 = bf_lo(u.z), v5 = bf_hi(u.z), v6 = bf_lo(u.w), v7 = bf_hi(u.w); \
      v0 = fmaxf(fmaf(v0, sc0.x, sh0.x), 0.f);                              \
      v1 = fmaxf(fmaf(v1, sc0.y, sh0.y), 0.f);                              \
      v2 = fmaxf(fmaf(v2, sc0.z, sh0.z), 0.f);                              \
      v3 = fmaxf(fmaf(v3, sc0.w, sh0.w), 0.f);                              \
      v4 = fmaxf(fmaf(v4, sc1.x, sh1.x), 0.f);                              \
      v5 = fmaxf(fmaf(v5, sc1.y, sh1.y), 0.f);                              \
      v6 = fmaxf(fmaf(v6, sc1.z, sh1.z), 0.f);                              \
      v7 = fmaxf(fmaf(v7, sc1.w, sh1.w), 0.f);                              \
      union { short8 s; unsigned u[4]; } pkd;                               \
      pkd.u[0] = pk2(v0, v1); pkd.u[1] = pk2(v2, v3);                       \
      pkd.u[2] = pk2(v4, v5); pkd.u[3] = pk2(v6, v7);                       \
      af[ks][m] = pkd.s;                                                    \
    }                                                                       \
  }

#define MFMAH(WsH)                                                          \
  _Pragma("unroll")                                                         \
  for (int ksl = 0; ksl < 4; ++ksl) {                                       \
    short8 bv[8];                                                           \
    _Pragma("unroll")                                                       \
    for (int n = 0; n < 8; ++n) {                                           \
      const int ro = n * 16 + lm;                                           \
      const int byt = (ksl * 64 + lg * 16) ^ ((ro & 7) << 4);               \
      bv[n] = *(const short8*)((WsH) + ro * 256 + byt);                     \
    }                                                                       \
    _Pragma("unroll")                                                       \
    for (int m = 0; m < 2; ++m)                                             \
      _Pragma("unroll")                                                     \
      for (int n = 0; n < 8; ++n)                                           \
        acc[m][n] = __builtin_amdgcn_mfma_f32_16x16x32_bf16(af[ksl][m],     \
                        bv[n], acc[m][n], 0, 0, 0);                         \
  }

  // issue A half-0 batch NOW (latency hides under W-stage drain + barrier)
  LOADH(0)

  f32x4 acc[2][8];
#pragma unroll
  for (int m = 0; m < 2; ++m)
#pragma unroll
    for (int n = 0; n < 8; ++n) acc[m][n] = (f32x4){0.f, 0.f, 0.f, 0.f};

  __syncthreads();   // W half-0 + scl/shf ready

  // issue W half-1 staging; its latency hides under MFMA_H0
#pragma unroll
  for (int i = 0; i < 8; ++i) {
    const int row = i * 16 + srow;
    gll16(Wrow + (size_t)row * 512 + 256 + gsb, Ws1 + row * 256 + sb);
  }

  CONVH(0)           // raw -> af (frees lu)
  LOADH(4)           // issue A half-1 batch before compute
  MFMAH(Ws0)         // 64 MFMAs on half-0
  CONVH(4)           // A half-1 (mostly arrived under MFMA)
  __syncthreads();   // W half-1 staged (vmcnt drained)
  MFMAH(Ws1)         // 64 MFMAs on half-1

  if (MODE == 0) {
    // ---- BN1 column partial stats from f32 acc ----
#pragma unroll
    for (int n = 0; n < 8; ++n) {
      float ss = 0, qq = 0;
#pragma unroll
      for (int m = 0; m < 2; ++m)
#pragma unroll
        for (int j = 0; j < 4; ++j) {
          float v = acc[m][n][j] + bregs[n];
          ss += v; qq += v * v;
        }
      ss += __shfl_xor(ss, 16); ss += __shfl_xor(ss, 32);
      qq += __shfl_xor(qq, 16); qq += __shfl_xor(qq, 32);
      if (lg == 0) {
        sstat[0][wid][n][lm] = ss;
        sstat[1][wid][n][lm] = qq;
      }
    }
  }
  __syncthreads();   // all Ws reads done + sstat written; Ws reusable as Cs

  // ---- C -> LDS f32 [128][128], swz col^(((row>>2)&3)<<4) -> 2-way max ----
  float* Cs = (float*)&Ws[0][0];   // 64KB
#pragma unroll
  for (int m = 0; m < 2; ++m) {
    const int rbase = wid * 32 + m * 16 + lg * 4;
    const int xd = lg << 4;        // == ((rbase>>2)&3)<<4
#pragma unroll
    for (int n = 0; n < 8; ++n) {
      const int col = n * 16 + lm;
#pragma unroll
      for (int j = 0; j < 4; ++j)
        Cs[(rbase + j) * 128 + (col ^ xd)] = acc[m][n][j] + bregs[n];
    }
  }
  __syncthreads();

  // ---- coalesced writeout: 16 thr/row, 16 rows/pass, 8 passes ----
  const int prow = t >> 4;          // 0..15
  const int pcol = (t & 15) * 8;    // 0..120
#pragma unroll
  for (int rb = 0; rb < 8; ++rb) {
    const int row = rb * 16 + prow;
    const int xd = ((row >> 2) & 3) << 4;
    f32x4 v0 = *(const f32x4*)&Cs[row * 128 + (pcol ^ xd)];
    f32x4 v1 = *(const f32x4*)&Cs[row * 128 + ((pcol + 4) ^ xd)];
    if (MODE == 0) {
      // ybf in (c,n,f): block slab is sequential
      const size_t gofs = (size_t)c * (NROWS * FDIM)
                        + (size_t)(bm * 128 + row) * FDIM + bn * 128 + pcol;
      uint4 u;
      u.x = pk2(v0[0], v0[1]); u.y = pk2(v0[2], v0[3]);
      u.z = pk2(v1[0], v1[1]); u.w = pk2(v1[2], v1[3]);
      *(uint4*)(Ybf + gofs) = u;
    } else {
      const size_t gofs = (size_t)(bm * 128 + row) * CF + c * FDIM + bn * 128 + pcol;
      float4 x0 = *(const float4*)(xres + gofs);
      float4 x1 = *(const float4*)(xres + gofs + 4);
      float4 o0, o1;
      o0.x = x0.x + v0[0]; o0.y = x0.y + v0[1]; o0.z = x0.z + v0[2]; o0.w = x0.w + v0[3];
      o1.x = x1.x + v1[0]; o1.y = x1.y + v1[1]; o1.z = x1.z + v1[2]; o1.w = x1.w + v1[3];
      *(float4*)(outf + gofs) = o0;
      *(float4*)(outf + gofs + 4) = o1;
    }
  }

  if (MODE == 0) {
    // ---- partial stats writeout: 256 thr = 2 stats x 128 cols ----
    const int stat = t >> 7;
    const int idx = t & 127;
    const int n = idx >> 4, lmm = idx & 15;
    float v = sstat[stat][0][n][lmm] + sstat[stat][1][n][lmm] +
              sstat[stat][2][n][lmm] + sstat[stat][3][n][lmm];
    float* dst = stat ? pq1 : ps1;
    dst[(size_t)bm * CF + c * FDIM + bn * 128 + n * 16 + lmm] = v;
  }
}

// ---------------- launch ----------------
extern "C" void kernel_launch(void* const* d_in, const int* in_sizes, int n_in,
                              void* d_out, int out_size, void* d_ws, size_t ws_size,
                              hipStream_t stream) {
  const float* x   = (const float*)d_in[0];
  const float* w0  = (const float*)d_in[1];
  const float* b0  = (const float*)d_in[2];
  const float* w1  = (const float*)d_in[3];
  const float* b1  = (const float*)d_in[4];
  const float* g0  = (const float*)d_in[5];
  const float* be0 = (const float*)d_in[6];
  const float* g1  = (const float*)d_in[7];
  const float* be1 = (const float*)d_in[8];
  float* out = (float*)d_out;

  char* ws = (char*)d_ws;
  float* ps0    = (float*)ws;                         // 16*CF
  float* pq0    = ps0 + (size_t)16 * CF;              // 16*CF
  float* ps1    = pq0 + (size_t)16 * CF;              // 16*CF
  float* pq1    = ps1 + (size_t)16 * CF;              // 16*CF
  float* scale0 = pq1 + (size_t)16 * CF;
  float* shift0 = scale0 + CF;
  float* scale1 = shift0 + CF;
  float* shift1 = scale1 + CF;
  ushort* w0bf = (ushort*)(shift1 + CF);
  ushort* w1bf = w0bf + (size_t)CCH * FDIM * FDIM;
  ushort* xt   = w1bf + (size_t)CCH * FDIM * FDIM;    // (c,n,f) bf16, 67MB
  ushort* ybf  = xt + (size_t)NROWS * CF;             // (c,n,f) bf16, 67MB

  const int NW4 = CCH * FDIM * FDIM / 4;
  cvt2_f32_bf16<<<4096, 256, 0, stream>>>(w0, w1, w0bf, w1bf, NW4);

  // BN0 stats + x -> xt (c,n,f) bf16
  stats_xt<<<dim3(64, 16), 256, 0, stream>>>(x, xt, ps0, pq0);
  bn_finalize<<<64, 256, 0, stream>>>(ps0, pq0, 16, g0, be0, scale0, shift0);

  // linear0 fused: A=relu(bn0(xt)), out ybf (c,n,f) + BN1 partials
  gemm_fused<0><<<2048, 256, 0, stream>>>(
      xt, w0bf, b0, scale0, shift0, nullptr, ybf, nullptr, ps1, pq1);

  bn_finalize<<<64, 256, 0, stream>>>(ps1, pq1, 16, g1, be1, scale1, shift1);

  // linear1 fused: A=relu(bn1(ybf)), out(n,cf) = x + acc + b1
  gemm_fused<1><<<2048, 256, 0, stream>>>(
      ybf, w1bf, b1, scale1, shift1, x, nullptr, out, nullptr, nullptr);
}

// Round 13
// 202.911 us; speedup vs baseline: 1.0927x; 1.0200x over previous
//
#include <hip/hip_runtime.h>
#include <hip/hip_bf16.h>

#define NROWS 2048
#define CCH   64
#define FDIM  256
#define CF    16384   // C*F
#define EPSV  1e-3f

typedef __attribute__((ext_vector_type(8))) short  short8;
typedef __attribute__((ext_vector_type(4))) float  f32x4;

__device__ __forceinline__ ushort f2bf(float f) {
  union { float f; unsigned u; } v; v.f = f;
  unsigned r = v.u + 0x7fffu + ((v.u >> 16) & 1u);
  return (ushort)(r >> 16);
}
__device__ __forceinline__ float bf_lo(unsigned u) {
  union { unsigned u; float f; } v; v.u = u << 16; return v.f;
}
__device__ __forceinline__ float bf_hi(unsigned u) {
  union { unsigned u; float f; } v; v.u = u & 0xffff0000u; return v.f;
}
__device__ __forceinline__ unsigned pk2(float a, float b) {
  __hip_bfloat162 h = __float22bfloat162_rn(float2{a, b});
  union { __hip_bfloat162 h; unsigned u; } cv; cv.h = h; return cv.u;
}
__device__ __forceinline__ void gll16(const void* g, void* l) {
  __builtin_amdgcn_global_load_lds(
      (const __attribute__((address_space(1))) unsigned*)g,
      (__attribute__((address_space(3))) unsigned*)l, 16, 0, 0);
}

// ---------------- BN0 stats + x -> xt bf16 (c,n,f) transpose-pack ----------------
__global__ __launch_bounds__(256) void stats_xt(const float* __restrict__ x,
                                                ushort* __restrict__ xt,
                                                float* __restrict__ ps,
                                                float* __restrict__ pq) {
  __shared__ float red[2][4][64][4];   // 8KB
  const int c  = blockIdx.x;
  const int nb = blockIdx.y;
  const int t  = threadIdx.x;
  const int cg = t & 63;               // float4 col group: f = cg*4..cg*4+3
  const int rg = t >> 6;               // 0..3

  const float4* src = (const float4*)x;         // idx = row*4096 + c*64 + cg
  ushort4* dst = (ushort4*)xt;                  // idx = c*131072 + row*64 + cg
  float s0 = 0, s1 = 0, s2 = 0, s3 = 0, q0 = 0, q1 = 0, q2 = 0, q3 = 0;
#pragma unroll 8
  for (int i = 0; i < 32; ++i) {
    const int row = nb * 128 + rg * 32 + i;
    float4 v = src[(size_t)row * 4096 + c * 64 + cg];
    s0 += v.x; q0 += v.x * v.x;
    s1 += v.y; q1 += v.y * v.y;
    s2 += v.z; q2 += v.z * v.z;
    s3 += v.w; q3 += v.w * v.w;
    ushort4 u;
    u.x = f2bf(v.x); u.y = f2bf(v.y); u.z = f2bf(v.z); u.w = f2bf(v.w);
    dst[(size_t)c * 131072 + row * 64 + cg] = u;
  }
  red[0][rg][cg][0] = s0; red[0][rg][cg][1] = s1;
  red[0][rg][cg][2] = s2; red[0][rg][cg][3] = s3;
  red[1][rg][cg][0] = q0; red[1][rg][cg][1] = q1;
  red[1][rg][cg][2] = q2; red[1][rg][cg][3] = q3;
  __syncthreads();
  if (t < 128) {
    const int which = t >> 6;          // 0=s, 1=q
    const int g = t & 63;
    float* dstp = which ? pq : ps;
#pragma unroll
    for (int j = 0; j < 4; ++j) {
      float v = red[which][0][g][j] + red[which][1][g][j] +
                red[which][2][g][j] + red[which][3][g][j];
      dstp[(size_t)nb * CF + c * FDIM + g * 4 + j] = v;
    }
  }
}

// reduce nparts partials -> scale/shift. grid 64 x 256.
__global__ __launch_bounds__(256) void bn_finalize(const float* __restrict__ ps,
                                                   const float* __restrict__ pq,
                                                   int nparts,
                                                   const float* __restrict__ g,
                                                   const float* __restrict__ be,
                                                   float* __restrict__ scale,
                                                   float* __restrict__ shift) {
  int i = blockIdx.x * 256 + threadIdx.x;
  float s = 0, q = 0;
  for (int j = 0; j < nparts; ++j) {
    s += ps[(size_t)j * CF + i];
    q += pq[(size_t)j * CF + i];
  }
  float mean = s * (1.0f / NROWS);
  float var  = q * (1.0f / NROWS) - mean * mean;
  float sc   = g[i] * rsqrtf(var + EPSV);
  scale[i] = sc;
  shift[i] = be[i] - mean * sc;
}

// ---------------- both weights f32 -> bf16, one launch ----------------
__global__ __launch_bounds__(256) void cvt2_f32_bf16(const float* __restrict__ w0,
                                                     const float* __restrict__ w1,
                                                     ushort* __restrict__ o0,
                                                     ushort* __restrict__ o1, int n4) {
  size_t stride = (size_t)gridDim.x * blockDim.x;
  for (size_t i = (size_t)blockIdx.x * 256 + threadIdx.x; i < (size_t)(2 * n4); i += stride) {
    const float* src = (i < (size_t)n4) ? w0 : w1;
    ushort* dst = (i < (size_t)n4) ? o0 : o1;
    size_t j = (i < (size_t)n4) ? i : i - n4;
    float4 v = ((const float4*)src)[j];
    ushort4 u;
    u.x = f2bf(v.x); u.y = f2bf(v.y); u.z = f2bf(v.z); u.w = f2bf(v.w);
    ((ushort4*)dst)[j] = u;
  }
}

// ---------------- fused batched channel GEMM: one-drain schedule ----------------
// Tile: BM=128 x BN=128 x K=256. Grid 2048 = 16bm x 2bn x 64c. 4 waves, each
// 32 rows x 128 cols (m=2, n=8 frags). ALL loads issue at t=0: 16 W gll16
// (both k-halves, XOR-swizzled src) + 16 A uint4 (full wave A-tile -> 64 VGPR).
// ONE vmcnt(0)+barrier, then 128 MFMAs with zero barriers / zero global loads.
// LDS caps 2 blocks/CU (8 waves) -> VGPR up to 256 is free; ~190 used.
// MODE 0: A=relu(bn0(xt)); epi: ybf (c,n,f) bf16 + BN1 partials.
// MODE 1: A=relu(bn1(ybf)); epi: out(n,cf) = xres + acc + bias.
template <int MODE>
__global__ __launch_bounds__(256, 2) void gemm_fused(const ushort* __restrict__ Act,
                                                     const ushort* __restrict__ W,
                                                     const float* __restrict__ bias,
                                                     const float* __restrict__ scale,
                                                     const float* __restrict__ shift,
                                                     const float* __restrict__ xres,
                                                     ushort* __restrict__ Ybf,
                                                     float* __restrict__ outf,
                                                     float* __restrict__ ps1,
                                                     float* __restrict__ pq1) {
  __shared__ __align__(16) ushort Ws[2][128 * 128];   // 64KB; reused as Cs f32[128][128]
  __shared__ float scl[256], shf[256];                // 2KB
  __shared__ float sstat[2][4][8][16];                // 4KB (MODE0)

  const int t = threadIdx.x;
  const int lane = t & 63, wid = t >> 6;
  const int lm = lane & 15, lg = lane >> 4;

  // bijective XCD swizzle (nwg=2048): XCD j gets wg in [j*256,(j+1)*256)
  const int h  = blockIdx.x;
  const int wg = ((h & 7) << 8) | (h >> 3);
  const int bm = wg & 15, bn = (wg >> 4) & 1, c = wg >> 5;

  // ---- issue ALL W staging now (both halves, 16 gll16/thread) ----
  const int srow = t >> 4;            // 0..15
  const int sb   = (t & 15) * 16;     // 0..240 byte-in-half-row
  const int gsb  = sb ^ ((srow & 7) << 4);
  const char* Wrow = (const char*)(W + ((size_t)c * FDIM + bn * 128) * FDIM);
  char* Ws0 = (char*)&Ws[0][0];
  char* Ws1 = (char*)&Ws[1][0];
#pragma unroll
  for (int i = 0; i < 8; ++i) {
    const int row = i * 16 + srow;
    gll16(Wrow + (size_t)row * 512 + gsb,       Ws0 + row * 256 + sb);
    gll16(Wrow + (size_t)row * 512 + 256 + gsb, Ws1 + row * 256 + sb);
  }

  // ---- issue ALL A loads now: full wave-tile, 16 uint4/lane (64 VGPR) ----
  const ushort* AbU[2];
#pragma unroll
  for (int m = 0; m < 2; ++m)
    AbU[m] = Act + (size_t)c * (NROWS * FDIM)
                 + (size_t)(bm * 128 + wid * 32 + m * 16 + lm) * FDIM + lg * 8;

  uint4 lu[8][2];
#pragma unroll
  for (int ks = 0; ks < 8; ++ks)
#pragma unroll
    for (int m = 0; m < 2; ++m)
      lu[ks][m] = *(const uint4*)(AbU[m] + ks * 32);
  __builtin_amdgcn_sched_barrier(0);

  scl[t] = scale[c * FDIM + t];
  shf[t] = shift[c * FDIM + t];

  float bregs[8];
#pragma unroll
  for (int n = 0; n < 8; ++n)
    bregs[n] = bias[c * FDIM + bn * 128 + n * 16 + lm];

  f32x4 acc[2][8];
#pragma unroll
  for (int m = 0; m < 2; ++m)
#pragma unroll
    for (int n = 0; n < 8; ++n) acc[m][n] = (f32x4){0.f, 0.f, 0.f, 0.f};

  __syncthreads();   // THE one drain: W (both halves) + A + scl/shf all ready

  short8 af[4][2];   // converted fragments for current half

#define CONVH(kb)                                                           \
  _Pragma("unroll")                                                         \
  for (int ks = 0; ks < 4; ++ks) {                                          \
    float4 sc0 = *(const float4*)&scl[((kb) + ks) * 32 + lg * 8];           \
    float4 sc1 = *(const float4*)&scl[((kb) + ks) * 32 + lg * 8 + 4];       \
    float4 sh0 = *(const float4*)&shf[((kb) + ks) * 32 + lg * 8];           \
    float4 sh1 = *(const float4*)&shf[((kb) + ks) * 32 + lg * 8 + 4];       \
    _Pragma("unroll")                                                       \
    for (int m = 0; m < 2; ++m) {                                           \
      uint4 u = lu[(kb) + ks][m];                                           \
      float v0 = bf_lo(u.x), v1 = bf_hi(u.x), v2 = bf_lo(u.y), v3 = bf_hi(u.y); \
      float v4 = bf_lo(u.z), v5 = bf_hi(u.z), v6 = bf_lo(u.w), v7 = bf_hi(u.w); \
      v0 = fmaxf(fmaf(v0, sc0.x, sh0.x), 0.f);                              \
      v1 = fmaxf(fmaf(v1, sc0.y, sh0.y), 0.f);                              \
      v2 = fmaxf(fmaf(v2, sc0.z, sh0.z), 0.f);                              \
      v3 = fmaxf(fmaf(v3, sc0.w, sh0.w), 0.f);                              \
      v4 = fmaxf(fmaf(v4, sc1.x, sh1.x), 0.f);                              \
      v5 = fmaxf(fmaf(v5, sc1.y, sh1.y), 0.f);                              \
      v6 = fmaxf(fmaf(v6, sc1.z, sh1.z), 0.f);                              \
      v7 = fmaxf(fmaf(v7, sc1.w, sh1.w), 0.f);                              \
      union { short8 s; unsigned u[4]; } pkd;                               \
      pkd.u[0] = pk2(v0, v1); pkd.u[1] = pk2(v2, v3);                       \
      pkd.u[2] = pk2(v4, v5); pkd.u[3] = pk2(v6, v7);                       \
      af[ks][m] = pkd.s;                                                    \
    }                                                                       \
  }

#define MFMAH(WsH)                                                          \
  _Pragma("unroll")                                                         \
  for (int ksl = 0; ksl < 4; ++ksl) {                                       \
    short8 bv[8];                                                           \
    _Pragma("unroll")                                                       \
    for (int n = 0; n < 8; ++n) {                                           \
      const int ro = n * 16 + lm;                                           \
      const int byt = (ksl * 64 + lg * 16) ^ ((ro & 7) << 4);               \
      bv[n] = *(const short8*)((WsH) + ro * 256 + byt);                     \
    }                                                                       \
    _Pragma("unroll")                                                       \
    for (int m = 0; m < 2; ++m)                                             \
      _Pragma("unroll")                                                     \
      for (int n = 0; n < 8; ++n)                                           \
        acc[m][n] = __builtin_amdgcn_mfma_f32_16x16x32_bf16(af[ksl][m],     \
                        bv[n], acc[m][n], 0, 0, 0);                         \
  }

  CONVH(0)
  MFMAH(Ws0)
  CONVH(4)
  MFMAH(Ws1)

  if (MODE == 0) {
    // ---- BN1 column partial stats from f32 acc ----
#pragma unroll
    for (int n = 0; n < 8; ++n) {
      float ss = 0, qq = 0;
#pragma unroll
      for (int m = 0; m < 2; ++m)
#pragma unroll
        for (int j = 0; j < 4; ++j) {
          float v = acc[m][n][j] + bregs[n];
          ss += v; qq += v * v;
        }
      ss += __shfl_xor(ss, 16); ss += __shfl_xor(ss, 32);
      qq += __shfl_xor(qq, 16); qq += __shfl_xor(qq, 32);
      if (lg == 0) {
        sstat[0][wid][n][lm] = ss;
        sstat[1][wid][n][lm] = qq;
      }
    }
  }
  __syncthreads();   // all Ws reads done + sstat written; Ws reusable as Cs

  // ---- C -> LDS f32 [128][128], swz col^(((row>>2)&3)<<4) -> 2-way max ----
  float* Cs = (float*)&Ws[0][0];   // 64KB
#pragma unroll
  for (int m = 0; m < 2; ++m) {
    const int rbase = wid * 32 + m * 16 + lg * 4;
    const int xd = lg << 4;        // == ((rbase>>2)&3)<<4
#pragma unroll
    for (int n = 0; n < 8; ++n) {
      const int col = n * 16 + lm;
#pragma unroll
      for (int j = 0; j < 4; ++j)
        Cs[(rbase + j) * 128 + (col ^ xd)] = acc[m][n][j] + bregs[n];
    }
  }
  __syncthreads();

  // ---- coalesced writeout: 16 thr/row, 16 rows/pass, 8 passes ----
  const int prow = t >> 4;          // 0..15
  const int pcol = (t & 15) * 8;    // 0..120
#pragma unroll
  for (int rb = 0; rb < 8; ++rb) {
    const int row = rb * 16 + prow;
    const int xd = ((row >> 2) & 3) << 4;
    f32x4 v0 = *(const f32x4*)&Cs[row * 128 + (pcol ^ xd)];
    f32x4 v1 = *(const f32x4*)&Cs[row * 128 + ((pcol + 4) ^ xd)];
    if (MODE == 0) {
      const size_t gofs = (size_t)c * (NROWS * FDIM)
                        + (size_t)(bm * 128 + row) * FDIM + bn * 128 + pcol;
      uint4 u;
      u.x = pk2(v0[0], v0[1]); u.y = pk2(v0[2], v0[3]);
      u.z = pk2(v1[0], v1[1]); u.w = pk2(v1[2], v1[3]);
      *(uint4*)(Ybf + gofs) = u;
    } else {
      const size_t gofs = (size_t)(bm * 128 + row) * CF + c * FDIM + bn * 128 + pcol;
      float4 x0 = *(const float4*)(xres + gofs);
      float4 x1 = *(const float4*)(xres + gofs + 4);
      float4 o0, o1;
      o0.x = x0.x + v0[0]; o0.y = x0.y + v0[1]; o0.z = x0.z + v0[2]; o0.w = x0.w + v0[3];
      o1.x = x1.x + v1[0]; o1.y = x1.y + v1[1]; o1.z = x1.z + v1[2]; o1.w = x1.w + v1[3];
      *(float4*)(outf + gofs) = o0;
      *(float4*)(outf + gofs + 4) = o1;
    }
  }

  if (MODE == 0) {
    // ---- partial stats writeout: 256 thr = 2 stats x 128 cols ----
    const int stat = t >> 7;
    const int idx = t & 127;
    const int n = idx >> 4, lmm = idx & 15;
    float v = sstat[stat][0][n][lmm] + sstat[stat][1][n][lmm] +
              sstat[stat][2][n][lmm] + sstat[stat][3][n][lmm];
    float* dst = stat ? pq1 : ps1;
    dst[(size_t)bm * CF + c * FDIM + bn * 128 + n * 16 + lmm] = v;
  }
}

// ---------------- launch ----------------
extern "C" void kernel_launch(void* const* d_in, const int* in_sizes, int n_in,
                              void* d_out, int out_size, void* d_ws, size_t ws_size,
                              hipStream_t stream) {
  const float* x   = (const float*)d_in[0];
  const float* w0  = (const float*)d_in[1];
  const float* b0  = (const float*)d_in[2];
  const float* w1  = (const float*)d_in[3];
  const float* b1  = (const float*)d_in[4];
  const float* g0  = (const float*)d_in[5];
  const float* be0 = (const float*)d_in[6];
  const float* g1  = (const float*)d_in[7];
  const float* be1 = (const float*)d_in[8];
  float* out = (float*)d_out;

  char* ws = (char*)d_ws;
  float* ps0    = (float*)ws;                         // 16*CF
  float* pq0    = ps0 + (size_t)16 * CF;              // 16*CF
  float* ps1    = pq0 + (size_t)16 * CF;              // 16*CF
  float* pq1    = ps1 + (size_t)16 * CF;              // 16*CF
  float* scale0 = pq1 + (size_t)16 * CF;
  float* shift0 = scale0 + CF;
  float* scale1 = shift0 + CF;
  float* shift1 = scale1 + CF;
  ushort* w0bf = (ushort*)(shift1 + CF);
  ushort* w1bf = w0bf + (size_t)CCH * FDIM * FDIM;
  ushort* xt   = w1bf + (size_t)CCH * FDIM * FDIM;    // (c,n,f) bf16, 67MB
  ushort* ybf  = xt + (size_t)NROWS * CF;             // (c,n,f) bf16, 67MB

  const int NW4 = CCH * FDIM * FDIM / 4;
  cvt2_f32_bf16<<<4096, 256, 0, stream>>>(w0, w1, w0bf, w1bf, NW4);

  // BN0 stats + x -> xt (c,n,f) bf16
  stats_xt<<<dim3(64, 16), 256, 0, stream>>>(x, xt, ps0, pq0);
  bn_finalize<<<64, 256, 0, stream>>>(ps0, pq0, 16, g0, be0, scale0, shift0);

  // linear0 fused: A=relu(bn0(xt)), out ybf (c,n,f) + BN1 partials
  gemm_fused<0><<<2048, 256, 0, stream>>>(
      xt, w0bf, b0, scale0, shift0, nullptr, ybf, nullptr, ps1, pq1);

  bn_finalize<<<64, 256, 0, stream>>>(ps1, pq1, 16, g1, be1, scale1, shift1);

  // linear1 fused: A=relu(bn1(ybf)), out(n,cf) = x + acc + b1
  gemm_fused<1><<<2048, 256, 0, stream>>>(
      ybf, w1bf, b1, scale1, shift1, x, nullptr, out, nullptr, nullptr);
}